// Round 12
// baseline (177.698 us; speedup 1.0000x reference)
//
#include <hip/hip_runtime.h>
#include <hip/hip_bf16.h>
#include <math.h>

constexpr int T_SEQ = 2049;
constexpr int D_MODEL = 1024;
constexpr int N_HEAD = 16;
constexpr int HEAD_DIM = 64;
constexpr int VT_STRIDE = 2112;  // V^T row length; s in [2049,2112) is garbage-but-finite (masked)
constexpr int T3_ROWS = 1409;    // rows 640..2048 for split partial buffers

typedef __attribute__((ext_vector_type(8))) short short8;
typedef __attribute__((ext_vector_type(4))) short short4v;
typedef __attribute__((ext_vector_type(4))) float floatx4;

// ---- flash partition tables: 38 slots/head, budget <=10 tiles/part ----
// qt 0-4: single part (direct ctx write, t<640); qt 5-9: 2 parts;
// qt 10-14: 3 parts; qt 15-16: 4 parts.  608 blocks total.
__device__ const int d_qt[38] = {0, 1, 2, 3, 4,  5, 5,  6, 6,  7, 7,  8, 8,
                                 9, 9,  10, 10, 10, 11, 11, 11, 12, 12, 12,
                                 13, 13, 13, 14, 14, 14, 15, 15, 15, 15,
                                 16, 16, 16, 16};
__device__ const int d_pt[38] = {0, 0, 0, 0, 0, 0, 1, 0, 1, 0, 1, 0, 1,
                                 0, 1, 0, 1, 2, 0, 1, 2, 0, 1, 2,
                                 0, 1, 2, 0, 1, 2, 0, 1, 2, 3,
                                 0, 1, 2, 3};
__device__ const int d_j0[38] = {0, 0, 0, 0, 0, 0, 6, 0, 7, 0, 8, 0, 9,
                                 0, 10, 0, 8, 16, 0, 8, 16, 0, 9, 18,
                                 0, 10, 19, 0, 10, 20, 0, 8, 16, 24,
                                 0, 9, 17, 25};
__device__ const int d_j1[38] = {1, 3, 5, 7, 9, 5, 11, 6, 13, 7, 15, 8, 17,
                                 9, 19, 7, 15, 21, 7, 15, 23, 8, 17, 25,
                                 9, 18, 27, 9, 19, 29, 7, 15, 23, 31,
                                 8, 16, 24, 32};
// heavy-first dispatch order (tile count descending: 10s,9s,8s,7s,6s,4,2)
__device__ const int d_ord[38] = {4, 13, 14, 24, 27, 28, 29,
                                  11, 12, 21, 22, 25, 26, 34,
                                  3, 9, 10, 15, 16, 18, 19, 20, 23, 30, 31,
                                  32, 33, 35, 36, 37,
                                  7, 8, 2, 5, 6, 17, 1, 0};

// async global->LDS, 16B per lane; LDS dest = wave-uniform base + lane*16
__device__ inline void load_lds16(const void* g, void* l) {
  __builtin_amdgcn_global_load_lds(
      (const __attribute__((address_space(1))) unsigned int*)g,
      (__attribute__((address_space(3))) unsigned int*)l, 16, 0, 0);
}

__device__ inline short8 cvt8_bf16(const float* p) {
  float4 a = *(const float4*)p, b = *(const float4*)(p + 4);
  __hip_bfloat16 t[8] = {__float2bfloat16(a.x), __float2bfloat16(a.y),
                         __float2bfloat16(a.z), __float2bfloat16(a.w),
                         __float2bfloat16(b.x), __float2bfloat16(b.y),
                         __float2bfloat16(b.z), __float2bfloat16(b.w)};
  return *(const short8*)t;
}

__device__ inline float bf2f(__hip_bfloat16 x) { return __bfloat162float(x); }

// ---------------------------------------------------------------------------
// Mega-cast: q,k,v,Wq,Wk,Wv,Er,Wo fp32->bf16 in one launch. grid=(1025,8)
// ---------------------------------------------------------------------------
__global__ __launch_bounds__(256) void cast_all(
    const float* __restrict__ q, const float* __restrict__ k,
    const float* __restrict__ v, const float* __restrict__ wq,
    const float* __restrict__ wk, const float* __restrict__ wv,
    const float* __restrict__ er, const float* __restrict__ wo,
    __hip_bfloat16* __restrict__ qo, __hip_bfloat16* __restrict__ ko,
    __hip_bfloat16* __restrict__ vo, __hip_bfloat16* __restrict__ wqo,
    __hip_bfloat16* __restrict__ wko, __hip_bfloat16* __restrict__ wvo,
    __hip_bfloat16* __restrict__ ero, __hip_bfloat16* __restrict__ woo) {
  const int z = blockIdx.y;
  const float* in;
  __hip_bfloat16* out;
  int n;
  switch (z) {
    case 0: in = q; out = qo; n = T_SEQ * D_MODEL; break;
    case 1: in = k; out = ko; n = T_SEQ * D_MODEL; break;
    case 2: in = v; out = vo; n = T_SEQ * D_MODEL; break;
    case 3: in = wq; out = wqo; n = D_MODEL * D_MODEL; break;
    case 4: in = wk; out = wko; n = D_MODEL * D_MODEL; break;
    case 5: in = wv; out = wvo; n = D_MODEL * D_MODEL; break;
    case 6: in = er; out = ero; n = T_SEQ * HEAD_DIM; break;
    default: in = wo; out = woo; n = D_MODEL * D_MODEL; break;
  }
  const int i = (blockIdx.x * 256 + threadIdx.x) * 8;
  if (i + 8 > n) return;
  *(short8*)(out + i) = cvt8_bf16(in + i);
}

// ---------------------------------------------------------------------------
// QKV GEMM, 8-WAVE blocks (512 thr) — round-5 exact (proven optimum of the
// occupancy/arith-intensity trade).  BK=32, dbuf global_load_lds, counted
// vmcnt(2), XCD panel swizzle.  z: 0,1 -> Q,K head-major; 2 -> V transposed.
// d>=408: Er rider.
// ---------------------------------------------------------------------------
__global__ __launch_bounds__(512) void qkv_gemm8(
    const __hip_bfloat16* __restrict__ qbf, const __hip_bfloat16* __restrict__ kbf,
    const __hip_bfloat16* __restrict__ vbf, const __hip_bfloat16* __restrict__ wqb,
    const __hip_bfloat16* __restrict__ wkb, const __hip_bfloat16* __restrict__ wvb,
    const float* __restrict__ bq, const float* __restrict__ bk,
    const float* __restrict__ bv, __hip_bfloat16* __restrict__ qpr,
    __hip_bfloat16* __restrict__ kpr, __hip_bfloat16* __restrict__ vt,
    const float* __restrict__ er, __hip_bfloat16* __restrict__ er_bf) {
  const int d = blockIdx.x;
  const int tid = threadIdx.x;
  if (d >= 408) {  // Er cast rider (33 blocks x 512 thr x 8 elems)
    const int i = ((d - 408) * 512 + tid) * 8;
    if (i + 8 <= T_SEQ * HEAD_DIM) *(short8*)(er_bf + i) = cvt8_bf16(er + i);
    return;
  }
  // ---- bijective XCD panel swizzle: 51 panels (y + 17z) x 8 col-blocks
  int x, p;
  if (d < 384) {
    const int g = d >> 6, rem = d & 63;
    x = rem >> 3;
    p = g * 8 + (rem & 7);
  } else {
    const int t = d - 384;
    p = 48 + (t >> 3);
    x = t & 7;
  }
  const int y = p % 17, z = p / 17;

  constexpr int K = D_MODEL, BK = 32;
  __shared__ __align__(16) char smem[32768];  // As[2][8K] | Bs[2][8K]

  const short* A = (const short*)(z == 0 ? qbf : z == 1 ? kbf : vbf);
  const short* W = (const short*)(z == 0 ? wqb : z == 1 ? wkb : wvb);
  const float* bias = z == 0 ? bq : z == 1 ? bk : bv;

  const int wave = tid >> 6, lane = tid & 63;
  const int col = lane & 15, quad = lane >> 4;
  const int wm = wave >> 2, wn = wave & 3;  // 2M x 4N, per-wave 64x32
  const int m0 = y * 128, n0 = x * 128;

  const int srow = wave * 16 + (lane >> 2);          // staged row 0..127
  const int sch = (lane & 3) ^ ((srow >> 1) & 3);    // swizzled 16B chunk
  const int am = min(m0 + srow, T_SEQ - 1);

#define STG(K0, BUF)                                                        \
  {                                                                         \
    load_lds16(A + (size_t)am * K + (K0) + sch * 8,                         \
               smem + (BUF)*8192 + wave * 1024);                            \
    load_lds16(W + (size_t)(n0 + srow) * K + (K0) + sch * 8,                \
               smem + 16384 + (BUF)*8192 + wave * 1024);                    \
  }

  floatx4 acc[4][2];
#pragma unroll
  for (int i = 0; i < 4; i++)
#pragma unroll
    for (int j = 0; j < 2; j++) acc[i][j] = (floatx4){0.f, 0.f, 0.f, 0.f};

  STG(0, 0)
  int buf = 0;
  for (int k0 = 0; k0 < K; k0 += BK, buf ^= 1) {
    if (k0 + BK < K) {
      STG(k0 + BK, buf ^ 1)
      asm volatile("s_waitcnt vmcnt(2)" ::: "memory");  // this stage landed
    } else {
      asm volatile("s_waitcnt vmcnt(0)" ::: "memory");
    }
    __builtin_amdgcn_s_barrier();

    const __hip_bfloat16* as = (const __hip_bfloat16*)(smem + buf * 8192);
    const __hip_bfloat16* bs = (const __hip_bfloat16*)(smem + 16384 + buf * 8192);
    short8 af[4], bfr[2];
#pragma unroll
    for (int t = 0; t < 4; t++) {
      const int ra = wm * 64 + t * 16 + col;
      af[t] = *(const short8*)(as + ra * 32 + ((quad ^ ((ra >> 1) & 3)) * 8));
    }
#pragma unroll
    for (int t = 0; t < 2; t++) {
      const int rb = wn * 32 + t * 16 + col;
      bfr[t] = *(const short8*)(bs + rb * 32 + ((quad ^ ((rb >> 1) & 3)) * 8));
    }
#pragma unroll
    for (int mt = 0; mt < 4; mt++)
#pragma unroll
      for (int nt = 0; nt < 2; nt++)
        acc[mt][nt] = __builtin_amdgcn_mfma_f32_16x16x32_bf16(af[mt], bfr[nt],
                                                              acc[mt][nt], 0, 0, 0);
    asm volatile("" ::: "memory");  // keep next STG below this iter's reads
    __builtin_amdgcn_s_barrier();
  }
#undef STG

  if (z == 2) {
    // ---- V transposed epilogue: acc -> LDS T[n][m] (swizzled) -> vt[h][hd][t]
    short* Tt = (short*)smem;  // 128(n) x 128(m) bf16 = 32 KB
#pragma unroll
    for (int mt = 0; mt < 4; mt++) {
      const int mb = wm * 16 + mt * 4 + quad;  // m-group of 4
#pragma unroll
      for (int nt = 0; nt < 2; nt++) {
        const int n = wn * 32 + nt * 16 + col;
        const float bb = bias[n0 + n];
        __hip_bfloat16 pk[4];
#pragma unroll
        for (int r = 0; r < 4; r++) pk[r] = __float2bfloat16(acc[mt][nt][r] + bb);
        *(short4v*)((char*)Tt + n * 256 + ((mb ^ (n & 15)) << 3)) =
            *(const short4v*)pk;
      }
    }
    __syncthreads();
    if (tid < 256) {
      const int n_loc = tid >> 1, half = tid & 1;
      if (m0 + half * 64 < VT_STRIDE) {
        const int ng = n0 + n_loc;
        __hip_bfloat16* dst = vt +
                              ((size_t)(ng >> 6) * HEAD_DIM + (ng & 63)) * VT_STRIDE +
                              m0 + half * 64;
#pragma unroll
        for (int c = 0; c < 8; c++) {
          short4v lo = *(const short4v*)((char*)Tt + n_loc * 256 +
                                         (((half * 16 + 2 * c) ^ (n_loc & 15)) << 3));
          short4v hi = *(const short4v*)((char*)Tt + n_loc * 256 +
                                         (((half * 16 + 2 * c + 1) ^ (n_loc & 15)) << 3));
          short8 o8 = {lo[0], lo[1], lo[2], lo[3], hi[0], hi[1], hi[2], hi[3]};
          *(short8*)((short*)dst + c * 8) = o8;
        }
      }
    }
    return;
  }

  // Q,K head-major epilogue
  __hip_bfloat16* C = z == 0 ? qpr : kpr;
#pragma unroll
  for (int mt = 0; mt < 4; mt++) {
#pragma unroll
    for (int r = 0; r < 4; r++) {
      const int m = m0 + wm * 64 + mt * 16 + quad * 4 + r;
      if (m >= T_SEQ) continue;
#pragma unroll
      for (int nt = 0; nt < 2; nt++) {
        const int n = n0 + wn * 32 + nt * 16 + col;
        const float val = acc[mt][nt][r] + bias[n];
        const int h = n >> 6, hd = n & 63;
        C[((size_t)h * T_SEQ + m) * HEAD_DIM + hd] = __float2bfloat16(val);
      }
    }
  }
}

// ---------------------------------------------------------------------------
// Output projection — round-5 exact.  64x64 tiles, 528 blocks, dbuf +
// counted-vmcnt, 16 KB LDS, XCD panel-swizzle.
// ---------------------------------------------------------------------------
__global__ __launch_bounds__(256) void out_gemm(
    const __hip_bfloat16* __restrict__ ctxb, const __hip_bfloat16* __restrict__ wob,
    const float* __restrict__ bias, float* __restrict__ out) {
  const int d = blockIdx.x;
  int x, p;
  if (d < 512) {
    const int g = d >> 7, rem = d & 127;
    x = rem >> 3;
    p = g * 8 + (rem & 7);
  } else {
    p = 32;
    x = d - 512;
  }
  const int m0 = p * 64, n0 = x * 64;

  constexpr int K = D_MODEL, BK = 32;
  __shared__ __align__(16) char smem[16384];  // As[2][4K] | Bs[2][4K]

  const int tid = threadIdx.x;
  const int wave = tid >> 6, lane = tid & 63;
  const int col = lane & 15, quad = lane >> 4;
  const int wm = wave >> 1, wn = wave & 1;  // 2M x 2N, per-wave 32x32

  const int srow = wave * 16 + (lane >> 2);        // staged row 0..63
  const int sch = (lane & 3) ^ ((srow >> 1) & 3);
  const int am = min(m0 + srow, T_SEQ - 1);
  const short* A = (const short*)ctxb;
  const short* W = (const short*)wob;

#define STG(K0, BUF)                                                        \
  {                                                                         \
    load_lds16(A + (size_t)am * K + (K0) + sch * 8,                         \
               smem + (BUF)*4096 + wave * 1024);                            \
    load_lds16(W + (size_t)(n0 + srow) * K + (K0) + sch * 8,                \
               smem + 8192 + (BUF)*4096 + wave * 1024);                     \
  }

  floatx4 acc[2][2];
#pragma unroll
  for (int i = 0; i < 2; i++)
#pragma unroll
    for (int j = 0; j < 2; j++) acc[i][j] = (floatx4){0.f, 0.f, 0.f, 0.f};

  STG(0, 0)
  int buf = 0;
  for (int k0 = 0; k0 < K; k0 += BK, buf ^= 1) {
    if (k0 + BK < K) {
      STG(k0 + BK, buf ^ 1)
      asm volatile("s_waitcnt vmcnt(2)" ::: "memory");
    } else {
      asm volatile("s_waitcnt vmcnt(0)" ::: "memory");
    }
    __builtin_amdgcn_s_barrier();

    const __hip_bfloat16* as = (const __hip_bfloat16*)(smem + buf * 4096);
    const __hip_bfloat16* bs = (const __hip_bfloat16*)(smem + 8192 + buf * 4096);
    short8 af[2], bfr[2];
#pragma unroll
    for (int t = 0; t < 2; t++) {
      const int ra = wm * 32 + t * 16 + col;
      af[t] = *(const short8*)(as + ra * 32 + ((quad ^ ((ra >> 1) & 3)) * 8));
    }
#pragma unroll
    for (int t = 0; t < 2; t++) {
      const int rb = wn * 32 + t * 16 + col;
      bfr[t] = *(const short8*)(bs + rb * 32 + ((quad ^ ((rb >> 1) & 3)) * 8));
    }
#pragma unroll
    for (int mt = 0; mt < 2; mt++)
#pragma unroll
      for (int nt = 0; nt < 2; nt++)
        acc[mt][nt] = __builtin_amdgcn_mfma_f32_16x16x32_bf16(af[mt], bfr[nt],
                                                              acc[mt][nt], 0, 0, 0);
    asm volatile("" ::: "memory");
    __builtin_amdgcn_s_barrier();
  }
#undef STG

#pragma unroll
  for (int mt = 0; mt < 2; mt++) {
#pragma unroll
    for (int r = 0; r < 4; r++) {
      const int m = m0 + wm * 32 + mt * 16 + quad * 4 + r;
      if (m >= T_SEQ) continue;
#pragma unroll
      for (int nt = 0; nt < 2; nt++) {
        const int n = n0 + wn * 32 + nt * 16 + col;
        out[(size_t)m * D_MODEL + n] = acc[mt][nt][r] + bias[n];
      }
    }
  }
}

// ---------------------------------------------------------------------------
// Flash attention v3 — inner loop round-8 exact; partition rebalanced to
// budget <=10 tiles/part (38 slots/head, 608 blocks; was <=12/33/528).
// Heavy-first ordering makes the 96 beyond-residency blocks the lightest.
// slot<5 (qt 0-4): complete sum -> direct normalized ctx (t<640).
// slot>=5: partial (O,l) into part buffer d_pt[slot] (rows t-640).
// ---------------------------------------------------------------------------
__global__ __launch_bounds__(512, 4) void flash_attn(
    const __hip_bfloat16* __restrict__ qh, const __hip_bfloat16* __restrict__ kh,
    const __hip_bfloat16* __restrict__ er, const __hip_bfloat16* __restrict__ vt,
    __hip_bfloat16* __restrict__ ctx, __hip_bfloat16* __restrict__ Obase,
    float* __restrict__ lbase) {
  __shared__ __align__(16) __hip_bfloat16 Ks[2][64 * 128];  // [s][kaug] swizzled
  __shared__ __align__(16) __hip_bfloat16 Vs[2][64 * 64];   // [d][s] swizzled
  __shared__ __align__(16) __hip_bfloat16 Ps[8][1024];      // per-wave frag-major

  const int tid = threadIdx.x;
  const int id = blockIdx.x + 38 * blockIdx.y;  // 0..607
  const int g = id >> 3;                        // 0..75
  const int h = (id & 7) + 8 * (g >= 38);       // XCD class id&7, 2 heads/class
  const int sraw = (g >= 38) ? g - 38 : g;
  const int slot = d_ord[sraw];                 // heavy-first
  const int qt = d_qt[slot];
  const int part = d_pt[slot];
  const bool single = (slot < 5);
  const int j0 = d_j0[slot], j1 = d_j1[slot];
  const int tq0 = qt * 128;

  const int wave = tid >> 6;
  const int lane = tid & 63;
  const int col = lane & 15;
  const int quad = lane >> 4;

  const short* qplane = (const short*)(qh + (size_t)h * T_SEQ * HEAD_DIM);
  const short* kplane = (const short*)(kh + (size_t)h * T_SEQ * HEAD_DIM);
  const short* eplane = (const short*)er;
  const short* vplane = (const short*)(vt + (size_t)h * HEAD_DIM * VT_STRIDE);

  const int t_abs = tq0 + wave * 16 + col;
  const int tload = min(t_abs, T_SEQ - 1);
  const bool hiz = (t_abs >= T_SEQ - 1);
  short8 aq[4];
#pragma unroll
  for (int kc = 0; kc < 4; kc++) {
    short8 v = *(const short8*)(qplane + (size_t)tload * 64 + kc * 32 + quad * 8);
    if (kc >= 2 && hiz) v = (short8){0, 0, 0, 0, 0, 0, 0, 0};
    aq[kc] = v;
  }

  floatx4 o[4];
  float l_lane = 0.f;
#pragma unroll
  for (int i = 0; i < 4; i++) o[i] = (floatx4){0.f, 0.f, 0.f, 0.f};

  const int tstrip = tq0 + wave * 16;
  __hip_bfloat16* psw = &Ps[wave][0];

#define STAGE_TILE(JJ, BUF)                                                        \
  {                                                                                \
    const int s0_ = (JJ) * 64;                                                     \
    _Pragma("unroll") for (int ii = 0; ii < 2; ii++) {                             \
      const int i_ = wave * 2 + ii;                                                \
      const int r_ = i_ * 4 + (lane >> 4);                                         \
      const int sl_ = lane & 15;                                                   \
      const int g_ = (sl_ & 8) | ((sl_ ^ (r_ & 7)) & 7);                           \
      const int s_ = min(s0_ + r_, T_SEQ - 1);                                     \
      const short* src_ = (g_ < 8) ? (kplane + (size_t)s_ * 64 + g_ * 8)           \
                                   : (eplane + (size_t)s_ * 64 + (g_ - 8) * 8);    \
      load_lds16(src_, (char*)&Ks[BUF][0] + i_ * 1024);                            \
    }                                                                              \
    {                                                                              \
      const int d_ = wave * 8 + (lane >> 3);                                       \
      const int sl_ = lane & 7;                                                    \
      const int g_ = sl_ ^ (d_ & 7);                                               \
      load_lds16(vplane + (size_t)d_ * VT_STRIDE + s0_ + g_ * 8,                   \
                 (char*)&Vs[BUF][0] + wave * 1024);                                \
    }                                                                              \
  }

  STAGE_TILE(j0, 0)
  int buf = 0;

  for (int j = j0; j <= j1; ++j, buf ^= 1) {
    __syncthreads();
    if (j < j1) STAGE_TILE(j + 1, buf ^ 1)

    const int s0 = j * 64;
    if (s0 > tstrip + 15) continue;

    const __hip_bfloat16* ks = &Ks[buf][0];
    const __hip_bfloat16* vs = &Vs[buf][0];

    floatx4 sacc[4];
    __builtin_amdgcn_s_setprio(1);
#pragma unroll
    for (int st = 0; st < 4; st++) {
      floatx4 c = {0.f, 0.f, 0.f, 0.f};
      const int row = st * 16 + col;
#pragma unroll
      for (int kc = 0; kc < 4; kc++) {
        const int ch = kc * 4 + quad;
        const int slot2 = (ch & 8) | ((ch ^ (row & 7)) & 7);
        short8 ka = *(const short8*)(ks + row * 128 + slot2 * 8);
        c = __builtin_amdgcn_mfma_f32_16x16x32_bf16(ka, aq[kc], c, 0, 0, 0);
      }
      sacc[st] = c;
    }
    __builtin_amdgcn_s_setprio(0);

    if (s0 + 63 > tstrip) {
#pragma unroll
      for (int st = 0; st < 4; st++) {
        const int sbase = s0 + st * 16 + quad * 4;
#pragma unroll
        for (int r = 0; r < 4; r++)
          if (sbase + r > t_abs) sacc[st][r] = -INFINITY;
      }
    }

    float rs = 0.f;
#pragma unroll
    for (int st = 0; st < 4; st++)
#pragma unroll
      for (int r = 0; r < 4; r++) {
        const float pql = __expf(sacc[st][r] * 0.125f);
        sacc[st][r] = pql;
        rs += pql;
      }
    l_lane += rs;

#pragma unroll
    for (int st = 0; st < 4; st++) {
      __hip_bfloat16 pb[4];
#pragma unroll
      for (int r = 0; r < 4; r++) pb[r] = __float2bfloat16(sacc[st][r]);
      const int kcA = st >> 1;
      const int quadA = (st & 1) * 2 + (quad >> 1);
      const int off = ((kcA * 4 + quadA) * 16 + col) * 8 + (quad & 1) * 4;
      *(short4v*)(psw + off) = *(const short4v*)pb;
    }
    short8 pa[2];
#pragma unroll
    for (int kc = 0; kc < 2; kc++)
      pa[kc] = *(const short8*)(psw + ((kc * 4 + quad) * 16 + col) * 8);

    __builtin_amdgcn_s_setprio(1);
#pragma unroll
    for (int nt = 0; nt < 4; nt++) {
      const int row = nt * 16 + col;
#pragma unroll
      for (int kc = 0; kc < 2; kc++) {
        const int slot2 = (kc * 4 + quad) ^ (row & 7);
        short8 vb = *(const short8*)(vs + row * 64 + slot2 * 8);
        o[nt] = __builtin_amdgcn_mfma_f32_16x16x32_bf16(pa[kc], vb, o[nt], 0, 0, 0);
      }
    }
    __builtin_amdgcn_s_setprio(0);
  }

  l_lane += __shfl_xor(l_lane, 16, 64);
  l_lane += __shfl_xor(l_lane, 32, 64);  // row-sum for t = tstrip + col

  if (single) {
    // complete sum: write normalized ctx directly (t < 640, all in-bounds)
    const float linv = 1.0f / l_lane;
    float linv_r[4];
#pragma unroll
    for (int r = 0; r < 4; r++) linv_r[r] = __shfl(linv, quad * 4 + r, 64);
#pragma unroll
    for (int r = 0; r < 4; r++) {
      const int t = tstrip + quad * 4 + r;
#pragma unroll
      for (int nt = 0; nt < 4; nt++)
        ctx[(size_t)t * D_MODEL + h * 64 + nt * 16 + col] =
            __float2bfloat16(o[nt][r] * linv_r[r]);
    }
  } else {
    // partial: store l and unnormalized O into part buffer (rows t-640)
    __hip_bfloat16* Op = Obase + (size_t)part * T3_ROWS * D_MODEL;
    float* lp = lbase + part * (N_HEAD * T3_ROWS);
    if (lane < 16) {
      const int t = tstrip + lane;
      if (t < T_SEQ) lp[h * T3_ROWS + (t - 640)] = l_lane;
    }
#pragma unroll
    for (int r = 0; r < 4; r++) {
      const int t = tstrip + quad * 4 + r;
      if (t < T_SEQ) {
        __hip_bfloat16* dst = Op + (size_t)(t - 640) * D_MODEL;
#pragma unroll
        for (int nt = 0; nt < 4; nt++)
          dst[h * 64 + nt * 16 + col] = __float2bfloat16(o[nt][r]);
      }
    }
  }
}

// ---------------------------------------------------------------------------
// finalize (t >= 640): ctx[t] = (sum_p O_p[t-640]) / (sum_p l_p)
// np = 2 for qt 5-9 (t < 1280), 3 for qt 10-14 (t < 1920), 4 for qt 15-16.
// ---------------------------------------------------------------------------
__global__ __launch_bounds__(256) void finalize(
    const __hip_bfloat16* __restrict__ Obase, const float* __restrict__ lbase,
    __hip_bfloat16* __restrict__ ctx) {
  const int idx = blockIdx.x * 256 + threadIdx.x;  // chunk index (8 elems)
  const int tr = idx >> 7;                         // row - 640
  const int t = 640 + tr;
  if (t >= T_SEQ) return;
  const int ch = idx & 127;
  const int h = ch >> 3;  // 8 chunks per 64-elem head
  const int qt = t >> 7;
  const int np = (qt >= 15) ? 4 : (qt >= 10) ? 3 : 2;

  float l = 0.f;
  float accv[8] = {0.f, 0.f, 0.f, 0.f, 0.f, 0.f, 0.f, 0.f};
  for (int p = 0; p < np; ++p) {
    l += lbase[p * (N_HEAD * T3_ROWS) + h * T3_ROWS + tr];
    const __hip_bfloat16* src =
        Obase + (size_t)p * T3_ROWS * D_MODEL + (size_t)tr * D_MODEL + ch * 8;
#pragma unroll
    for (int e = 0; e < 8; e++) accv[e] += bf2f(src[e]);
  }
  const float inv = 1.0f / l;
  __hip_bfloat16 outv[8];
#pragma unroll
  for (int e = 0; e < 8; e++) outv[e] = __float2bfloat16(accv[e] * inv);
  *(short8*)(ctx + (size_t)t * D_MODEL + ch * 8) = *(const short8*)outv;
}

// ---------------------------------------------------------------------------
extern "C" void kernel_launch(void* const* d_in, const int* in_sizes, int n_in,
                              void* d_out, int out_size, void* d_ws, size_t ws_size,
                              hipStream_t stream) {
  const float* q = (const float*)d_in[0];
  const float* k = (const float*)d_in[1];
  const float* v = (const float*)d_in[2];
  const float* Wq_w = (const float*)d_in[4];
  const float* Wq_b = (const float*)d_in[5];
  const float* Wk_w = (const float*)d_in[6];
  const float* Wk_b = (const float*)d_in[7];
  const float* Wv_w = (const float*)d_in[8];
  const float* Wv_b = (const float*)d_in[9];
  const float* Er = (const float*)d_in[10];
  const float* Wo_w = (const float*)d_in[11];
  const float* Wo_b = (const float*)d_in[12];
  float* out = (float*)d_out;

  // ---- workspace carve-up (round-8 layout; 4-part O/l overlays)
  char* ws = (char*)d_ws;
  const size_t sz_plane = (size_t)T_SEQ * D_MODEL * 2;            // 4,196,352
  const size_t sz_w = (size_t)D_MODEL * D_MODEL * 2;              // 2,097,152
  const size_t sz_vt = (size_t)N_HEAD * HEAD_DIM * VT_STRIDE * 2; // 4,325,376
  const size_t sz_er = (size_t)T_SEQ * HEAD_DIM * 2;              // 262,272
  const size_t sz_O3 = (size_t)T3_ROWS * D_MODEL * 2;             // 2,885,632

  // live through QKV GEMM:
  __hip_bfloat16* qbf = (__hip_bfloat16*)ws;
  __hip_bfloat16* kbf = (__hip_bfloat16*)(ws + sz_plane);
  __hip_bfloat16* vbf = (__hip_bfloat16*)(ws + 2 * sz_plane);
  __hip_bfloat16* wqb = (__hip_bfloat16*)(ws + 3 * sz_plane);
  __hip_bfloat16* wkb = (__hip_bfloat16*)(ws + 3 * sz_plane + sz_w);
  __hip_bfloat16* wvb = (__hip_bfloat16*)(ws + 3 * sz_plane + 2 * sz_w);
  char* hi = ws + 3 * sz_plane + 3 * sz_w;
  __hip_bfloat16* qpr = (__hip_bfloat16*)hi;                  // head-major Q
  __hip_bfloat16* kpr = (__hip_bfloat16*)(hi + sz_plane);     // head-major K
  __hip_bfloat16* vt = (__hip_bfloat16*)(hi + 2 * sz_plane);  // transposed V
  __hip_bfloat16* er_bf = (__hip_bfloat16*)(hi + 2 * sz_plane + sz_vt);
  __hip_bfloat16* wob = (__hip_bfloat16*)(hi + 2 * sz_plane + sz_vt + sz_er);

  // overlays on regions dead after QKV GEMM (Obase 4 parts = 11.5 MB ends at
  // ws+15.8MB < hi=ws+18.9MB; lbase 4x90KB after that):
  __hip_bfloat16* ctxb = (__hip_bfloat16*)ws;                 // ex-qbf
  __hip_bfloat16* Obase = (__hip_bfloat16*)(ws + sz_plane);   // ex-kbf/vbf/wqb
  float* lbase = (float*)(ws + sz_plane + 4 * sz_O3);

  const dim3 blk(256);

  // 1) fp32->bf16 casts (q,k,v,Wq,Wk,Wv,Er,Wo) in one launch
  cast_all<<<dim3(1025, 8), blk, 0, stream>>>(q, k, v, Wq_w, Wk_w, Wv_w, Er, Wo_w,
                                              qbf, kbf, vbf, wqb, wkb, wvb, er_bf,
                                              wob);

  // 2) fused QKV projections, 8-wave blocks + XCD panel swizzle + Er rider
  qkv_gemm8<<<dim3(441), dim3(512), 0, stream>>>(
      qbf, kbf, vbf, wqb, wkb, wvb, Wq_b, Wk_b, Wv_b, qpr, kpr, vt, Er, er_bf);

  // 3) flash attention, balanced 38-slot partition (<=10 tiles/block)
  flash_attn<<<dim3(38, N_HEAD), dim3(512), 0, stream>>>(qpr, kpr, er_bf, vt, ctxb,
                                                         Obase, lbase);

  // 4) merge 2-4 partial parts for t>=640
  finalize<<<dim3((T3_ROWS * 128 + 255) / 256), blk, 0, stream>>>(Obase, lbase,
                                                                  ctxb);

  // 5) output projection, 64x64 tiles + XCD panel swizzle (fp32 out)
  out_gemm<<<dim3(528), blk, 0, stream>>>(ctxb, wob, Wo_b, out);
}

// Round 13
// 175.076 us; speedup vs baseline: 1.0150x; 1.0150x over previous
//
#include <hip/hip_runtime.h>
#include <hip/hip_bf16.h>
#include <math.h>

constexpr int T_SEQ = 2049;
constexpr int D_MODEL = 1024;
constexpr int N_HEAD = 16;
constexpr int HEAD_DIM = 64;
constexpr int VT_STRIDE = 2112;  // V^T row length; s in [2049,2112) is garbage-but-finite (masked)
constexpr int T2_ROWS = 1281;    // rows 768..2048 for split partial buffers

typedef __attribute__((ext_vector_type(8))) short short8;
typedef __attribute__((ext_vector_type(4))) short short4v;
typedef __attribute__((ext_vector_type(4))) float floatx4;

// ---- flash partition tables: 33 slots/head, budget <=12 tiles/part ----
// qt 0-5: single part (direct ctx write, t<768); qt 6-11: 2 parts; 12-16: 3.
__device__ const int d_qt[33] = {0, 1, 2, 3, 4,  5,  6,  6,  7,  7,  8,
                                 8, 9, 9, 10, 10, 11, 11, 12, 12, 12, 13,
                                 13, 13, 14, 14, 14, 15, 15, 15, 16, 16, 16};
__device__ const int d_pt[33] = {0, 0, 0, 0, 0, 0, 0, 1, 0, 1, 0,
                                 1, 0, 1, 0, 1, 0, 1, 0, 1, 2, 0,
                                 1, 2, 0, 1, 2, 0, 1, 2, 0, 1, 2};
__device__ const int d_j0[33] = {0, 0, 0, 0, 0,  0,  0, 7, 0, 8, 0,
                                 9, 0, 10, 0, 11, 0, 12, 0, 8, 17, 0,
                                 9, 18, 0, 10, 20, 0, 10, 21, 0, 11, 22};
__device__ const int d_j1[33] = {1, 3, 5, 7, 9,  11, 6, 13, 7, 15, 8,
                                 17, 9, 19, 10, 21, 11, 23, 7, 16, 25, 8,
                                 17, 27, 9, 19, 29, 9, 20, 31, 10, 21, 32};
// heavy-first dispatch order (tile count descending)
__device__ const int d_ord[33] = {5, 16, 17, 14, 15, 28, 29, 30, 31, 32, 4,
                                  12, 13, 23, 24, 25, 26, 27, 10, 11, 19, 20,
                                  21, 22, 3, 8, 9, 18, 6, 7, 2, 1, 0};

// async global->LDS, 16B per lane; LDS dest = wave-uniform base + lane*16
__device__ inline void load_lds16(const void* g, void* l) {
  __builtin_amdgcn_global_load_lds(
      (const __attribute__((address_space(1))) unsigned int*)g,
      (__attribute__((address_space(3))) unsigned int*)l, 16, 0, 0);
}

__device__ inline short8 cvt8_bf16(const float* p) {
  float4 a = *(const float4*)p, b = *(const float4*)(p + 4);
  __hip_bfloat16 t[8] = {__float2bfloat16(a.x), __float2bfloat16(a.y),
                         __float2bfloat16(a.z), __float2bfloat16(a.w),
                         __float2bfloat16(b.x), __float2bfloat16(b.y),
                         __float2bfloat16(b.z), __float2bfloat16(b.w)};
  return *(const short8*)t;
}

__device__ inline float bf2f(__hip_bfloat16 x) { return __bfloat162float(x); }

// ---------------------------------------------------------------------------
// Mega-cast: q,k,v,Wq,Wk,Wv,Er,Wo fp32->bf16 in one launch. grid=(1025,8)
// ---------------------------------------------------------------------------
__global__ __launch_bounds__(256) void cast_all(
    const float* __restrict__ q, const float* __restrict__ k,
    const float* __restrict__ v, const float* __restrict__ wq,
    const float* __restrict__ wk, const float* __restrict__ wv,
    const float* __restrict__ er, const float* __restrict__ wo,
    __hip_bfloat16* __restrict__ qo, __hip_bfloat16* __restrict__ ko,
    __hip_bfloat16* __restrict__ vo, __hip_bfloat16* __restrict__ wqo,
    __hip_bfloat16* __restrict__ wko, __hip_bfloat16* __restrict__ wvo,
    __hip_bfloat16* __restrict__ ero, __hip_bfloat16* __restrict__ woo) {
  const int z = blockIdx.y;
  const float* in;
  __hip_bfloat16* out;
  int n;
  switch (z) {
    case 0: in = q; out = qo; n = T_SEQ * D_MODEL; break;
    case 1: in = k; out = ko; n = T_SEQ * D_MODEL; break;
    case 2: in = v; out = vo; n = T_SEQ * D_MODEL; break;
    case 3: in = wq; out = wqo; n = D_MODEL * D_MODEL; break;
    case 4: in = wk; out = wko; n = D_MODEL * D_MODEL; break;
    case 5: in = wv; out = wvo; n = D_MODEL * D_MODEL; break;
    case 6: in = er; out = ero; n = T_SEQ * HEAD_DIM; break;
    default: in = wo; out = woo; n = D_MODEL * D_MODEL; break;
  }
  const int i = (blockIdx.x * 256 + threadIdx.x) * 8;
  if (i + 8 > n) return;
  *(short8*)(out + i) = cvt8_bf16(in + i);
}

// ---------------------------------------------------------------------------
// QKV GEMM, 8-WAVE blocks (512 thr) — round-5 exact (proven optimum of the
// occupancy/arith-intensity trade: 128x128 tile, 3.2 waves/SIMD).
// BK=32, dbuf global_load_lds, counted vmcnt(2), XCD panel swizzle.
// z: 0,1 -> Q,K head-major; 2 -> V transposed.  d>=408: Er rider.
// ---------------------------------------------------------------------------
__global__ __launch_bounds__(512) void qkv_gemm8(
    const __hip_bfloat16* __restrict__ qbf, const __hip_bfloat16* __restrict__ kbf,
    const __hip_bfloat16* __restrict__ vbf, const __hip_bfloat16* __restrict__ wqb,
    const __hip_bfloat16* __restrict__ wkb, const __hip_bfloat16* __restrict__ wvb,
    const float* __restrict__ bq, const float* __restrict__ bk,
    const float* __restrict__ bv, __hip_bfloat16* __restrict__ qpr,
    __hip_bfloat16* __restrict__ kpr, __hip_bfloat16* __restrict__ vt,
    const float* __restrict__ er, __hip_bfloat16* __restrict__ er_bf) {
  const int d = blockIdx.x;
  const int tid = threadIdx.x;
  if (d >= 408) {  // Er cast rider (33 blocks x 512 thr x 8 elems)
    const int i = ((d - 408) * 512 + tid) * 8;
    if (i + 8 <= T_SEQ * HEAD_DIM) *(short8*)(er_bf + i) = cvt8_bf16(er + i);
    return;
  }
  // ---- bijective XCD panel swizzle: 51 panels (y + 17z) x 8 col-blocks
  int x, p;
  if (d < 384) {
    const int g = d >> 6, rem = d & 63;
    x = rem >> 3;
    p = g * 8 + (rem & 7);
  } else {
    const int t = d - 384;
    p = 48 + (t >> 3);
    x = t & 7;
  }
  const int y = p % 17, z = p / 17;

  constexpr int K = D_MODEL, BK = 32;
  __shared__ __align__(16) char smem[32768];  // As[2][8K] | Bs[2][8K]

  const short* A = (const short*)(z == 0 ? qbf : z == 1 ? kbf : vbf);
  const short* W = (const short*)(z == 0 ? wqb : z == 1 ? wkb : wvb);
  const float* bias = z == 0 ? bq : z == 1 ? bk : bv;

  const int wave = tid >> 6, lane = tid & 63;
  const int col = lane & 15, quad = lane >> 4;
  const int wm = wave >> 2, wn = wave & 3;  // 2M x 4N, per-wave 64x32
  const int m0 = y * 128, n0 = x * 128;

  const int srow = wave * 16 + (lane >> 2);          // staged row 0..127
  const int sch = (lane & 3) ^ ((srow >> 1) & 3);    // swizzled 16B chunk
  const int am = min(m0 + srow, T_SEQ - 1);

#define STG(K0, BUF)                                                        \
  {                                                                         \
    load_lds16(A + (size_t)am * K + (K0) + sch * 8,                         \
               smem + (BUF)*8192 + wave * 1024);                            \
    load_lds16(W + (size_t)(n0 + srow) * K + (K0) + sch * 8,                \
               smem + 16384 + (BUF)*8192 + wave * 1024);                    \
  }

  floatx4 acc[4][2];
#pragma unroll
  for (int i = 0; i < 4; i++)
#pragma unroll
    for (int j = 0; j < 2; j++) acc[i][j] = (floatx4){0.f, 0.f, 0.f, 0.f};

  STG(0, 0)
  int buf = 0;
  for (int k0 = 0; k0 < K; k0 += BK, buf ^= 1) {
    if (k0 + BK < K) {
      STG(k0 + BK, buf ^ 1)
      asm volatile("s_waitcnt vmcnt(2)" ::: "memory");  // this stage landed
    } else {
      asm volatile("s_waitcnt vmcnt(0)" ::: "memory");
    }
    __builtin_amdgcn_s_barrier();

    const __hip_bfloat16* as = (const __hip_bfloat16*)(smem + buf * 8192);
    const __hip_bfloat16* bs = (const __hip_bfloat16*)(smem + 16384 + buf * 8192);
    short8 af[4], bfr[2];
#pragma unroll
    for (int t = 0; t < 4; t++) {
      const int ra = wm * 64 + t * 16 + col;
      af[t] = *(const short8*)(as + ra * 32 + ((quad ^ ((ra >> 1) & 3)) * 8));
    }
#pragma unroll
    for (int t = 0; t < 2; t++) {
      const int rb = wn * 32 + t * 16 + col;
      bfr[t] = *(const short8*)(bs + rb * 32 + ((quad ^ ((rb >> 1) & 3)) * 8));
    }
#pragma unroll
    for (int mt = 0; mt < 4; mt++)
#pragma unroll
      for (int nt = 0; nt < 2; nt++)
        acc[mt][nt] = __builtin_amdgcn_mfma_f32_16x16x32_bf16(af[mt], bfr[nt],
                                                              acc[mt][nt], 0, 0, 0);
    asm volatile("" ::: "memory");  // keep next STG below this iter's reads
    __builtin_amdgcn_s_barrier();
  }
#undef STG

  if (z == 2) {
    // ---- V transposed epilogue: acc -> LDS T[n][m] (swizzled) -> vt[h][hd][t]
    short* Tt = (short*)smem;  // 128(n) x 128(m) bf16 = 32 KB
#pragma unroll
    for (int mt = 0; mt < 4; mt++) {
      const int mb = wm * 16 + mt * 4 + quad;  // m-group of 4
#pragma unroll
      for (int nt = 0; nt < 2; nt++) {
        const int n = wn * 32 + nt * 16 + col;
        const float bb = bias[n0 + n];
        __hip_bfloat16 pk[4];
#pragma unroll
        for (int r = 0; r < 4; r++) pk[r] = __float2bfloat16(acc[mt][nt][r] + bb);
        *(short4v*)((char*)Tt + n * 256 + ((mb ^ (n & 15)) << 3)) =
            *(const short4v*)pk;
      }
    }
    __syncthreads();
    if (tid < 256) {
      const int n_loc = tid >> 1, half = tid & 1;
      if (m0 + half * 64 < VT_STRIDE) {
        const int ng = n0 + n_loc;
        __hip_bfloat16* dst = vt +
                              ((size_t)(ng >> 6) * HEAD_DIM + (ng & 63)) * VT_STRIDE +
                              m0 + half * 64;
#pragma unroll
        for (int c = 0; c < 8; c++) {
          short4v lo = *(const short4v*)((char*)Tt + n_loc * 256 +
                                         (((half * 16 + 2 * c) ^ (n_loc & 15)) << 3));
          short4v hi = *(const short4v*)((char*)Tt + n_loc * 256 +
                                         (((half * 16 + 2 * c + 1) ^ (n_loc & 15)) << 3));
          short8 o8 = {lo[0], lo[1], lo[2], lo[3], hi[0], hi[1], hi[2], hi[3]};
          *(short8*)((short*)dst + c * 8) = o8;
        }
      }
    }
    return;
  }

  // Q,K head-major epilogue
  __hip_bfloat16* C = z == 0 ? qpr : kpr;
#pragma unroll
  for (int mt = 0; mt < 4; mt++) {
#pragma unroll
    for (int r = 0; r < 4; r++) {
      const int m = m0 + wm * 64 + mt * 16 + quad * 4 + r;
      if (m >= T_SEQ) continue;
#pragma unroll
      for (int nt = 0; nt < 2; nt++) {
        const int n = n0 + wn * 32 + nt * 16 + col;
        const float val = acc[mt][nt][r] + bias[n];
        const int h = n >> 6, hd = n & 63;
        C[((size_t)h * T_SEQ + m) * HEAD_DIM + hd] = __float2bfloat16(val);
      }
    }
  }
}

// ---------------------------------------------------------------------------
// Output projection — round-5 exact.  64x64 tiles, 528 blocks, dbuf +
// counted-vmcnt, 16 KB LDS, XCD panel-swizzle.
// ---------------------------------------------------------------------------
__global__ __launch_bounds__(256) void out_gemm(
    const __hip_bfloat16* __restrict__ ctxb, const __hip_bfloat16* __restrict__ wob,
    const float* __restrict__ bias, float* __restrict__ out) {
  const int d = blockIdx.x;
  int x, p;
  if (d < 512) {
    const int g = d >> 7, rem = d & 127;
    x = rem >> 3;
    p = g * 8 + (rem & 7);
  } else {
    p = 32;
    x = d - 512;
  }
  const int m0 = p * 64, n0 = x * 64;

  constexpr int K = D_MODEL, BK = 32;
  __shared__ __align__(16) char smem[16384];  // As[2][4K] | Bs[2][4K]

  const int tid = threadIdx.x;
  const int wave = tid >> 6, lane = tid & 63;
  const int col = lane & 15, quad = lane >> 4;
  const int wm = wave >> 1, wn = wave & 1;  // 2M x 2N, per-wave 32x32

  const int srow = wave * 16 + (lane >> 2);        // staged row 0..63
  const int sch = (lane & 3) ^ ((srow >> 1) & 3);
  const int am = min(m0 + srow, T_SEQ - 1);
  const short* A = (const short*)ctxb;
  const short* W = (const short*)wob;

#define STG(K0, BUF)                                                        \
  {                                                                         \
    load_lds16(A + (size_t)am * K + (K0) + sch * 8,                         \
               smem + (BUF)*4096 + wave * 1024);                            \
    load_lds16(W + (size_t)(n0 + srow) * K + (K0) + sch * 8,                \
               smem + 8192 + (BUF)*4096 + wave * 1024);                     \
  }

  floatx4 acc[2][2];
#pragma unroll
  for (int i = 0; i < 2; i++)
#pragma unroll
    for (int j = 0; j < 2; j++) acc[i][j] = (floatx4){0.f, 0.f, 0.f, 0.f};

  STG(0, 0)
  int buf = 0;
  for (int k0 = 0; k0 < K; k0 += BK, buf ^= 1) {
    if (k0 + BK < K) {
      STG(k0 + BK, buf ^ 1)
      asm volatile("s_waitcnt vmcnt(2)" ::: "memory");
    } else {
      asm volatile("s_waitcnt vmcnt(0)" ::: "memory");
    }
    __builtin_amdgcn_s_barrier();

    const __hip_bfloat16* as = (const __hip_bfloat16*)(smem + buf * 4096);
    const __hip_bfloat16* bs = (const __hip_bfloat16*)(smem + 8192 + buf * 4096);
    short8 af[2], bfr[2];
#pragma unroll
    for (int t = 0; t < 2; t++) {
      const int ra = wm * 32 + t * 16 + col;
      af[t] = *(const short8*)(as + ra * 32 + ((quad ^ ((ra >> 1) & 3)) * 8));
    }
#pragma unroll
    for (int t = 0; t < 2; t++) {
      const int rb = wn * 32 + t * 16 + col;
      bfr[t] = *(const short8*)(bs + rb * 32 + ((quad ^ ((rb >> 1) & 3)) * 8));
    }
#pragma unroll
    for (int mt = 0; mt < 2; mt++)
#pragma unroll
      for (int nt = 0; nt < 2; nt++)
        acc[mt][nt] = __builtin_amdgcn_mfma_f32_16x16x32_bf16(af[mt], bfr[nt],
                                                              acc[mt][nt], 0, 0, 0);
    asm volatile("" ::: "memory");
    __builtin_amdgcn_s_barrier();
  }
#undef STG

#pragma unroll
  for (int mt = 0; mt < 2; mt++) {
#pragma unroll
    for (int r = 0; r < 4; r++) {
      const int m = m0 + wm * 32 + mt * 16 + quad * 4 + r;
      if (m >= T_SEQ) continue;
#pragma unroll
      for (int nt = 0; nt < 2; nt++) {
        const int n = n0 + wn * 32 + nt * 16 + col;
        out[(size_t)m * D_MODEL + n] = acc[mt][nt][r] + bias[n];
      }
    }
  }
}

// ---------------------------------------------------------------------------
// Flash attention v3 — round-8 exact: S^T trick + no-max softmax + async
// staged K/V (prefetched a tile ahead — off the critical path) + 33-slot
// balanced partition (<=12 tiles/block), heavy-first, XCD swizzle.
// slot<6 (qt 0-5): complete sum -> direct normalized ctx (t<768).
// slot>=6: partial (O,l) into part buffer d_pt[slot] (rows t-768).
// ---------------------------------------------------------------------------
__global__ __launch_bounds__(512, 4) void flash_attn(
    const __hip_bfloat16* __restrict__ qh, const __hip_bfloat16* __restrict__ kh,
    const __hip_bfloat16* __restrict__ er, const __hip_bfloat16* __restrict__ vt,
    __hip_bfloat16* __restrict__ ctx, __hip_bfloat16* __restrict__ Obase,
    float* __restrict__ lbase) {
  __shared__ __align__(16) __hip_bfloat16 Ks[2][64 * 128];  // [s][kaug] swizzled
  __shared__ __align__(16) __hip_bfloat16 Vs[2][64 * 64];   // [d][s] swizzled
  __shared__ __align__(16) __hip_bfloat16 Ps[8][1024];      // per-wave frag-major

  const int tid = threadIdx.x;
  const int id = blockIdx.x + 33 * blockIdx.y;  // 0..527
  const int g = id >> 3;                        // 0..65
  const int h = (id & 7) + 8 * (g >= 33);       // XCD class id&7, 2 heads/class
  const int sraw = (g >= 33) ? g - 33 : g;
  const int slot = d_ord[sraw];                 // heavy-first
  const int qt = d_qt[slot];
  const int part = d_pt[slot];
  const bool single = (slot < 6);
  const int j0 = d_j0[slot], j1 = d_j1[slot];
  const int tq0 = qt * 128;

  const int wave = tid >> 6;
  const int lane = tid & 63;
  const int col = lane & 15;
  const int quad = lane >> 4;

  const short* qplane = (const short*)(qh + (size_t)h * T_SEQ * HEAD_DIM);
  const short* kplane = (const short*)(kh + (size_t)h * T_SEQ * HEAD_DIM);
  const short* eplane = (const short*)er;
  const short* vplane = (const short*)(vt + (size_t)h * HEAD_DIM * VT_STRIDE);

  const int t_abs = tq0 + wave * 16 + col;
  const int tload = min(t_abs, T_SEQ - 1);
  const bool hiz = (t_abs >= T_SEQ - 1);
  short8 aq[4];
#pragma unroll
  for (int kc = 0; kc < 4; kc++) {
    short8 v = *(const short8*)(qplane + (size_t)tload * 64 + kc * 32 + quad * 8);
    if (kc >= 2 && hiz) v = (short8){0, 0, 0, 0, 0, 0, 0, 0};
    aq[kc] = v;
  }

  floatx4 o[4];
  float l_lane = 0.f;
#pragma unroll
  for (int i = 0; i < 4; i++) o[i] = (floatx4){0.f, 0.f, 0.f, 0.f};

  const int tstrip = tq0 + wave * 16;
  __hip_bfloat16* psw = &Ps[wave][0];

#define STAGE_TILE(JJ, BUF)                                                        \
  {                                                                                \
    const int s0_ = (JJ) * 64;                                                     \
    _Pragma("unroll") for (int ii = 0; ii < 2; ii++) {                             \
      const int i_ = wave * 2 + ii;                                                \
      const int r_ = i_ * 4 + (lane >> 4);                                         \
      const int sl_ = lane & 15;                                                   \
      const int g_ = (sl_ & 8) | ((sl_ ^ (r_ & 7)) & 7);                           \
      const int s_ = min(s0_ + r_, T_SEQ - 1);                                     \
      const short* src_ = (g_ < 8) ? (kplane + (size_t)s_ * 64 + g_ * 8)           \
                                   : (eplane + (size_t)s_ * 64 + (g_ - 8) * 8);    \
      load_lds16(src_, (char*)&Ks[BUF][0] + i_ * 1024);                            \
    }                                                                              \
    {                                                                              \
      const int d_ = wave * 8 + (lane >> 3);                                       \
      const int sl_ = lane & 7;                                                    \
      const int g_ = sl_ ^ (d_ & 7);                                               \
      load_lds16(vplane + (size_t)d_ * VT_STRIDE + s0_ + g_ * 8,                   \
                 (char*)&Vs[BUF][0] + wave * 1024);                                \
    }                                                                              \
  }

  STAGE_TILE(j0, 0)
  int buf = 0;

  for (int j = j0; j <= j1; ++j, buf ^= 1) {
    __syncthreads();
    if (j < j1) STAGE_TILE(j + 1, buf ^ 1)

    const int s0 = j * 64;
    if (s0 > tstrip + 15) continue;

    const __hip_bfloat16* ks = &Ks[buf][0];
    const __hip_bfloat16* vs = &Vs[buf][0];

    floatx4 sacc[4];
    __builtin_amdgcn_s_setprio(1);
#pragma unroll
    for (int st = 0; st < 4; st++) {
      floatx4 c = {0.f, 0.f, 0.f, 0.f};
      const int row = st * 16 + col;
#pragma unroll
      for (int kc = 0; kc < 4; kc++) {
        const int ch = kc * 4 + quad;
        const int slot2 = (ch & 8) | ((ch ^ (row & 7)) & 7);
        short8 ka = *(const short8*)(ks + row * 128 + slot2 * 8);
        c = __builtin_amdgcn_mfma_f32_16x16x32_bf16(ka, aq[kc], c, 0, 0, 0);
      }
      sacc[st] = c;
    }
    __builtin_amdgcn_s_setprio(0);

    if (s0 + 63 > tstrip) {
#pragma unroll
      for (int st = 0; st < 4; st++) {
        const int sbase = s0 + st * 16 + quad * 4;
#pragma unroll
        for (int r = 0; r < 4; r++)
          if (sbase + r > t_abs) sacc[st][r] = -INFINITY;
      }
    }

    float rs = 0.f;
#pragma unroll
    for (int st = 0; st < 4; st++)
#pragma unroll
      for (int r = 0; r < 4; r++) {
        const float pql = __expf(sacc[st][r] * 0.125f);
        sacc[st][r] = pql;
        rs += pql;
      }
    l_lane += rs;

#pragma unroll
    for (int st = 0; st < 4; st++) {
      __hip_bfloat16 pb[4];
#pragma unroll
      for (int r = 0; r < 4; r++) pb[r] = __float2bfloat16(sacc[st][r]);
      const int kcA = st >> 1;
      const int quadA = (st & 1) * 2 + (quad >> 1);
      const int off = ((kcA * 4 + quadA) * 16 + col) * 8 + (quad & 1) * 4;
      *(short4v*)(psw + off) = *(const short4v*)pb;
    }
    short8 pa[2];
#pragma unroll
    for (int kc = 0; kc < 2; kc++)
      pa[kc] = *(const short8*)(psw + ((kc * 4 + quad) * 16 + col) * 8);

    __builtin_amdgcn_s_setprio(1);
#pragma unroll
    for (int nt = 0; nt < 4; nt++) {
      const int row = nt * 16 + col;
#pragma unroll
      for (int kc = 0; kc < 2; kc++) {
        const int slot2 = (kc * 4 + quad) ^ (row & 7);
        short8 vb = *(const short8*)(vs + row * 64 + slot2 * 8);
        o[nt] = __builtin_amdgcn_mfma_f32_16x16x32_bf16(pa[kc], vb, o[nt], 0, 0, 0);
      }
    }
    __builtin_amdgcn_s_setprio(0);
  }

  l_lane += __shfl_xor(l_lane, 16, 64);
  l_lane += __shfl_xor(l_lane, 32, 64);  // row-sum for t = tstrip + col

  if (single) {
    // complete sum: write normalized ctx directly (t < 768, all in-bounds)
    const float linv = 1.0f / l_lane;
    float linv_r[4];
#pragma unroll
    for (int r = 0; r < 4; r++) linv_r[r] = __shfl(linv, quad * 4 + r, 64);
#pragma unroll
    for (int r = 0; r < 4; r++) {
      const int t = tstrip + quad * 4 + r;
#pragma unroll
      for (int nt = 0; nt < 4; nt++)
        ctx[(size_t)t * D_MODEL + h * 64 + nt * 16 + col] =
            __float2bfloat16(o[nt][r] * linv_r[r]);
    }
  } else {
    // partial: store l and unnormalized O into part buffer (rows t-768)
    __hip_bfloat16* Op = Obase + (size_t)part * T2_ROWS * D_MODEL;
    float* lp = lbase + part * (N_HEAD * T2_ROWS);
    if (lane < 16) {
      const int t = tstrip + lane;
      if (t < T_SEQ) lp[h * T2_ROWS + (t - 768)] = l_lane;
    }
#pragma unroll
    for (int r = 0; r < 4; r++) {
      const int t = tstrip + quad * 4 + r;
      if (t < T_SEQ) {
        __hip_bfloat16* dst = Op + (size_t)(t - 768) * D_MODEL;
#pragma unroll
        for (int nt = 0; nt < 4; nt++)
          dst[h * 64 + nt * 16 + col] = __float2bfloat16(o[nt][r]);
      }
    }
  }
}

// ---------------------------------------------------------------------------
// finalize (t >= 768): ctx[t] = (sum_p O_p[t-768]) / (sum_p l_p)
// np = 2 for qt 6-11 (t < 1536), 3 for qt 12-16.
// ---------------------------------------------------------------------------
__global__ __launch_bounds__(256) void finalize(
    const __hip_bfloat16* __restrict__ Obase, const float* __restrict__ lbase,
    __hip_bfloat16* __restrict__ ctx) {
  const int idx = blockIdx.x * 256 + threadIdx.x;  // chunk index (8 elems)
  const int tr = idx >> 7;                         // row - 768
  const int t = 768 + tr;
  if (t >= T_SEQ) return;
  const int ch = idx & 127;
  const int h = ch >> 3;  // 8 chunks per 64-elem head
  const int np = ((t >> 7) >= 12) ? 3 : 2;

  float l = 0.f;
  float accv[8] = {0.f, 0.f, 0.f, 0.f, 0.f, 0.f, 0.f, 0.f};
  for (int p = 0; p < np; ++p) {
    l += lbase[p * (N_HEAD * T2_ROWS) + h * T2_ROWS + tr];
    const __hip_bfloat16* src =
        Obase + (size_t)p * T2_ROWS * D_MODEL + (size_t)tr * D_MODEL + ch * 8;
#pragma unroll
    for (int e = 0; e < 8; e++) accv[e] += bf2f(src[e]);
  }
  const float inv = 1.0f / l;
  __hip_bfloat16 outv[8];
#pragma unroll
  for (int e = 0; e < 8; e++) outv[e] = __float2bfloat16(accv[e] * inv);
  *(short8*)(ctx + (size_t)t * D_MODEL + ch * 8) = *(const short8*)outv;
}

// ---------------------------------------------------------------------------
extern "C" void kernel_launch(void* const* d_in, const int* in_sizes, int n_in,
                              void* d_out, int out_size, void* d_ws, size_t ws_size,
                              hipStream_t stream) {
  const float* q = (const float*)d_in[0];
  const float* k = (const float*)d_in[1];
  const float* v = (const float*)d_in[2];
  const float* Wq_w = (const float*)d_in[4];
  const float* Wq_b = (const float*)d_in[5];
  const float* Wk_w = (const float*)d_in[6];
  const float* Wk_b = (const float*)d_in[7];
  const float* Wv_w = (const float*)d_in[8];
  const float* Wv_b = (const float*)d_in[9];
  const float* Er = (const float*)d_in[10];
  const float* Wo_w = (const float*)d_in[11];
  const float* Wo_b = (const float*)d_in[12];
  float* out = (float*)d_out;

  // ---- workspace carve-up (round-8 layout)
  char* ws = (char*)d_ws;
  const size_t sz_plane = (size_t)T_SEQ * D_MODEL * 2;            // 4,196,352
  const size_t sz_w = (size_t)D_MODEL * D_MODEL * 2;              // 2,097,152
  const size_t sz_vt = (size_t)N_HEAD * HEAD_DIM * VT_STRIDE * 2; // 4,325,376
  const size_t sz_er = (size_t)T_SEQ * HEAD_DIM * 2;              // 262,272

  // live through QKV GEMM:
  __hip_bfloat16* qbf = (__hip_bfloat16*)ws;
  __hip_bfloat16* kbf = (__hip_bfloat16*)(ws + sz_plane);
  __hip_bfloat16* vbf = (__hip_bfloat16*)(ws + 2 * sz_plane);
  __hip_bfloat16* wqb = (__hip_bfloat16*)(ws + 3 * sz_plane);
  __hip_bfloat16* wkb = (__hip_bfloat16*)(ws + 3 * sz_plane + sz_w);
  __hip_bfloat16* wvb = (__hip_bfloat16*)(ws + 3 * sz_plane + 2 * sz_w);
  char* hi = ws + 3 * sz_plane + 3 * sz_w;
  __hip_bfloat16* qpr = (__hip_bfloat16*)hi;                  // head-major Q
  __hip_bfloat16* kpr = (__hip_bfloat16*)(hi + sz_plane);     // head-major K
  __hip_bfloat16* vt = (__hip_bfloat16*)(hi + 2 * sz_plane);  // transposed V
  __hip_bfloat16* er_bf = (__hip_bfloat16*)(hi + 2 * sz_plane + sz_vt);
  __hip_bfloat16* wob = (__hip_bfloat16*)(hi + 2 * sz_plane + sz_vt + sz_er);

  // overlays on regions dead after QKV GEMM:
  __hip_bfloat16* ctxb = (__hip_bfloat16*)ws;                 // ex-qbf
  __hip_bfloat16* Obase = (__hip_bfloat16*)(ws + sz_plane);   // ex-kbf/vbf, 3 parts
  float* lbase = (float*)(ws + 3 * sz_plane);                 // ex-wqb, 3 parts

  const dim3 blk(256);

  // 1) fp32->bf16 casts (q,k,v,Wq,Wk,Wv,Er,Wo) in one launch
  cast_all<<<dim3(1025, 8), blk, 0, stream>>>(q, k, v, Wq_w, Wk_w, Wv_w, Er, Wo_w,
                                              qbf, kbf, vbf, wqb, wkb, wvb, er_bf,
                                              wob);

  // 2) fused QKV projections, 8-wave blocks + XCD panel swizzle + Er rider
  qkv_gemm8<<<dim3(441), dim3(512), 0, stream>>>(
      qbf, kbf, vbf, wqb, wkb, wvb, Wq_b, Wk_b, Wv_b, qpr, kpr, vt, Er, er_bf);

  // 3) flash attention, balanced 33-slot partition (<=12 tiles/block)
  flash_attn<<<dim3(33, N_HEAD), dim3(512), 0, stream>>>(qpr, kpr, er_bf, vt, ctxb,
                                                         Obase, lbase);

  // 4) merge 2-3 partial parts for t>=768
  finalize<<<dim3((T2_ROWS * 128 + 255) / 256), blk, 0, stream>>>(Obase, lbase,
                                                                  ctxb);

  // 5) output projection, 64x64 tiles + XCD panel swizzle (fp32 out)
  out_gemm<<<dim3(528), blk, 0, stream>>>(ctxb, wob, Wo_b, out);
}